// Round 13
// baseline (1262.790 us; speedup 1.0000x reference)
//
#include <hip/hip_runtime.h>
#include <hip/hip_bf16.h>

#define BB 8
#define NN 2048
#define KK 20
#define BN (BB*NN)
#define RSQ 0.99999500003749969f   // 1/sqrt(1+1e-5)

// ---------------- workspace layout (float-slot units), 44.7 MiB baseline ----------------
constexpr size_t OFF_XX  = 0;                          // BN
constexpr size_t OFF_X1  = OFF_XX  + BN;               // BN*64
constexpr size_t OFF_X2  = OFF_X1  + (size_t)BN*64;    // BN*64
constexpr size_t OFF_X3  = OFF_X2  + (size_t)BN*64;    // BN*128
constexpr size_t OFF_X4  = OFF_X3  + (size_t)BN*128;   // BN*256
constexpr size_t OFF_SC  = OFF_X4  + (size_t)BN*256;   // BN*160 (q,bs chunked/L1)
constexpr size_t OFF_ID  = OFF_SC  + (size_t)BN*160;   // int BN*20
constexpr size_t OFF_W5T = OFF_ID  + (size_t)BN*20;    // 512*512
constexpr size_t OFF_MX  = OFF_W5T + 512*512;
constexpr size_t OFF_MN  = OFF_MX  + BB*512;
constexpr size_t OFF_WT2 = OFF_MN  + BB*512;           // [128][64]
constexpr size_t OFF_WT3 = OFF_WT2 + 8192;             // [128][128]
constexpr size_t OFF_WT4 = OFF_WT3 + 16384;            // [256][256]
constexpr size_t WS_END  = OFF_WT4 + 65536;            // 11,714,560 floats
// big region (probed at runtime): 8-batch dist; later reused as full q/bs
constexpr size_t OFF_BIG = WS_END;
constexpr size_t WS_BIG_END = OFF_BIG + (size_t)BB*NN*NN;   // 172.7 MiB
static_assert(OFF_ID - OFF_X3 >= (size_t)4096*2048, "fallback dual dist fits");

__device__ inline unsigned encf(float f){ unsigned u=__float_as_uint(f); return (u&0x80000000u)? ~u : (u|0x80000000u); }
__device__ inline float decf(unsigned e){ unsigned u=(e&0x80000000u)? (e&0x7fffffffu) : ~e; return __uint_as_float(u); }
__device__ inline float lrelu(float h){ return h>=0.f ? h : 0.2f*h; }

// ---------------- prep ----------------
__global__ void prep_k(const float* W5, const float* W2, const float* W3, const float* W4,
                       float* W5T, float* WT2, float* WT3, float* WT4,
                       unsigned* mx, unsigned* mn){
  int i = blockIdx.x*256 + threadIdx.x;     // 262144
  { int o = i>>9, c = i&511; W5T[c*512+o] = W5[i]; }
  if(i < 65536){ int o = i>>8, c = i&255; WT4[c*256+o] = W4[i]; }
  if(i < 16384){ int o = i>>7, c = i&127; WT3[c*128+o] = W3[i]; }
  if(i <  8192){ int o = i>>7, c = i&127; WT2[c*64 +o] = W2[i]; }
  if(i <  4096){ mx[i] = 0x007FFFFFu; mn[i] = 0xFF800000u; }
}

// ---------------- KNN ----------------
template<int C>
__launch_bounds__(256) __global__ void sqnorm_k(const float* X, float* xx){
  int i = blockIdx.x*256 + threadIdx.x;   // BN
  const float* r = X + (size_t)i*C;
  float s = 0.f;
  #pragma unroll
  for(int c=0;c<C;c++) s = fmaf(r[c], r[c], s);
  xx[i] = s;
}

#define FMA_ROW(I) \
  acc[I][0]=fmaf(a,b0v,acc[I][0]); acc[I][1]=fmaf(a,b1v,acc[I][1]); \
  acc[I][2]=fmaf(a,b2v,acc[I][2]); acc[I][3]=fmaf(a,b3v,acc[I][3]); \
  acc[I][4]=fmaf(a,b4v,acc[I][4]); acc[I][5]=fmaf(a,b5v,acc[I][5]); \
  acc[I][6]=fmaf(a,b6v,acc[I][6]); acc[I][7]=fmaf(a,b7v,acc[I][7]);

template<int C>
__launch_bounds__(256) __global__ void gemm_dist_k(const float* __restrict__ X, const float* __restrict__ xx,
                                                   float* __restrict__ dist, int b0){
  constexpr int AST = 188;
  __shared__ __align__(16) float a_sh[16*AST];
  __shared__ __align__(16) float b_sh[16*AST];
  __shared__ float sxn[128], sxm[128];
  const int tid = threadIdx.x;
  const int b   = b0 + blockIdx.z;
  const int mtile = blockIdx.x*128;
  const int ntile = blockIdx.y*128;
  const int tn = tid & 15, tm = tid >> 4;
  const float* Xb  = X  + (size_t)b*NN*C;
  const float* xxb = xx + (size_t)b*NN;
  if(tid < 128) sxn[tid] = xxb[ntile + tid];
  else          sxm[tid-128] = xxb[mtile + tid-128];
  float acc[8][8];
  #pragma unroll
  for(int i=0;i<8;i++){
    #pragma unroll
    for(int j=0;j<8;j++) acc[i][j]=0.f;
  }
  for(int cc=0; cc<C; cc+=16){
    __syncthreads();
    #pragma unroll
    for(int s=0;s<2;s++){
      int ii = tid + 256*s; int r = ii>>2, q = ii&3;
      int pr = r + 4*(r>>3);
      float4 va = *(const float4*)&Xb[(size_t)(ntile + r)*C + cc + 4*q];
      a_sh[(4*q+0)*AST + pr]=va.x; a_sh[(4*q+1)*AST + pr]=va.y;
      a_sh[(4*q+2)*AST + pr]=va.z; a_sh[(4*q+3)*AST + pr]=va.w;
      float4 vb = *(const float4*)&Xb[(size_t)(mtile + r)*C + cc + 4*q];
      b_sh[(4*q+0)*AST + pr]=vb.x; b_sh[(4*q+1)*AST + pr]=vb.y;
      b_sh[(4*q+2)*AST + pr]=vb.z; b_sh[(4*q+3)*AST + pr]=vb.w;
    }
    __syncthreads();
    #pragma unroll
    for(int c=0;c<16;c++){
      float4 A0 = *(const float4*)&a_sh[c*AST + 12*tn];
      float4 A1 = *(const float4*)&a_sh[c*AST + 12*tn + 4];
      float4 B0 = *(const float4*)&b_sh[c*AST + 12*tm];
      float4 B1 = *(const float4*)&b_sh[c*AST + 12*tm + 4];
      float b0v=B0.x,b1v=B0.y,b2v=B0.z,b3v=B0.w,b4v=B1.x,b5v=B1.y,b6v=B1.z,b7v=B1.w;
      float a;
      a=A0.x; FMA_ROW(0)
      a=A0.y; FMA_ROW(1)
      a=A0.z; FMA_ROW(2)
      a=A0.w; FMA_ROW(3)
      a=A1.x; FMA_ROW(4)
      a=A1.y; FMA_ROW(5)
      a=A1.z; FMA_ROW(6)
      a=A1.w; FMA_ROW(7)
    }
  }
  float xnr[8], xmr[8];
  #pragma unroll
  for(int i=0;i<8;i++){ xnr[i]=sxn[tn*8+i]; xmr[i]=sxm[tm*8+i]; }
  const size_t rowb = (size_t)blockIdx.z*NN + ntile + tn*8;
  #pragma unroll
  for(int i=0;i<8;i++){
    float4 w0, w1;
    w0.x=(2.f*acc[i][0]-xnr[i])-xmr[0]; w0.y=(2.f*acc[i][1]-xnr[i])-xmr[1];
    w0.z=(2.f*acc[i][2]-xnr[i])-xmr[2]; w0.w=(2.f*acc[i][3]-xnr[i])-xmr[3];
    w1.x=(2.f*acc[i][4]-xnr[i])-xmr[4]; w1.y=(2.f*acc[i][5]-xnr[i])-xmr[5];
    w1.z=(2.f*acc[i][6]-xnr[i])-xmr[6]; w1.w=(2.f*acc[i][7]-xnr[i])-xmr[7];
    float* dp = dist + (rowb + i)*NN + mtile + tm*8;
    *(float4*)dp = w0;
    *(float4*)(dp+4) = w1;
  }
}

// Wave-cooperative top-20 (sorted in lanes 0..19)
__launch_bounds__(256) __global__ void sel_k(const float* __restrict__ dist, int* __restrict__ id,
                                             int b0, int nrows){
  const int w = (blockIdx.x*256 + threadIdx.x) >> 6;
  const int lane = threadIdx.x & 63;
  if(w >= nrows) return;
  const float* dr = dist + (size_t)w*NN;
  float lv = -INFINITY; int li = 0;
  float theta = -INFINITY;
  for(int ms=0; ms<NN; ms+=64){
    float cand = dr[ms + lane];
    unsigned long long bal = __ballot(cand > theta);
    while(bal){
      int bpos = __ffsll((unsigned long long)bal) - 1;
      bal &= bal - 1;
      float cv = __shfl(cand, bpos);
      if(cv > theta){
        int ci = ms + bpos;
        unsigned long long mge = __ballot(lv >= cv);
        int pos = __popcll(mge);
        float upv = __shfl_up(lv, 1);
        int   upi = __shfl_up(li, 1);
        bool shift = (lane > pos) && (lane < KK);
        lv = (lane == pos) ? cv : (shift ? upv : lv);
        li = (lane == pos) ? ci : (shift ? upi : li);
        theta = __shfl(lv, KK-1);
      }
    }
  }
  if(lane < KK) id[((size_t)b0*NN + w)*KK + lane] = li;
}

// L1 fused: inline C=3 distances AND inline sqnorm (xx not materialized for L1).
__launch_bounds__(256) __global__ void sel3_k(const float* __restrict__ X, int* __restrict__ id){
  const int gw = (blockIdx.x*256 + threadIdx.x) >> 6;
  const int lane = threadIdx.x & 63;
  const int b = gw >> 11, n = gw & 2047;
  const float* Xb  = X + (size_t)b*NN*3;
  const float x0v = Xb[n*3], x1v = Xb[n*3+1], x2v = Xb[n*3+2];
  float xxn = 0.f;
  xxn = fmaf(x0v, x0v, xxn); xxn = fmaf(x1v, x1v, xxn); xxn = fmaf(x2v, x2v, xxn);
  float lv = -INFINITY; int li = 0;
  float theta = -INFINITY;
  for(int ms=0; ms<NN; ms+=64){
    int m = ms + lane;
    float m0 = Xb[m*3+0], m1 = Xb[m*3+1], m2 = Xb[m*3+2];
    float s = 0.f;
    s = fmaf(x0v, m0, s); s = fmaf(x1v, m1, s); s = fmaf(x2v, m2, s);
    float xxm = 0.f;
    xxm = fmaf(m0, m0, xxm); xxm = fmaf(m1, m1, xxm); xxm = fmaf(m2, m2, xxm);
    float cand = (2.f*s - xxn) - xxm;
    unsigned long long bal = __ballot(cand > theta);
    while(bal){
      int bpos = __ffsll((unsigned long long)bal) - 1;
      bal &= bal - 1;
      float cv = __shfl(cand, bpos);
      if(cv > theta){
        int ci = ms + bpos;
        unsigned long long mge = __ballot(lv >= cv);
        int pos = __popcll(mge);
        float upv = __shfl_up(lv, 1);
        int   upi = __shfl_up(li, 1);
        bool shift = (lane > pos) && (lane < KK);
        lv = (lane == pos) ? cv : (shift ? upv : lv);
        li = (lane == pos) ? ci : (shift ? upi : li);
        theta = __shfl(lv, KK-1);
      }
    }
  }
  if(lane < KK) id[(size_t)gw*KK + lane] = li;
}

// ---------------- qp ----------------
__launch_bounds__(256) __global__ void qp3_k(const float* X, const float* W,
                                             float* q, float* bs){
  const int t   = blockIdx.x*256 + threadIdx.x;
  const int row = t >> 3;
  const int c0  = (t & 7) * 8;
  float xn[3];
  #pragma unroll
  for(int c=0;c<3;c++) xn[c] = X[(size_t)row*3 + c];
  for(int oi=c0; oi<c0+8; oi++){
    const float* w = W + (size_t)oi*6;
    float aq=0.f, ap=0.f;
    #pragma unroll
    for(int c=0;c<3;c++){ aq = fmaf(xn[c], w[c], aq); ap = fmaf(xn[c], w[3+c], ap); }
    q [(size_t)row*64 + oi] = aq;
    bs[(size_t)row*64 + oi] = ap - aq;
  }
}

// chunked (fallback) qp: q/bs width 64
template<int CIN, int COUT>
__launch_bounds__(256) __global__ void qp64T_k(const float* __restrict__ X, const float* __restrict__ WT,
                                               int cb, float* __restrict__ q, float* __restrict__ bs){
  const int t   = blockIdx.x*256 + threadIdx.x;
  const int row = t >> 3;
  const int o0  = cb + (t & 7) * 8;
  float xn[CIN];
  #pragma unroll
  for(int c=0;c<CIN;c+=4){ float4 v = *(const float4*)(X + (size_t)row*CIN + c);
    xn[c]=v.x; xn[c+1]=v.y; xn[c+2]=v.z; xn[c+3]=v.w; }
  float aq[8], ap[8];
  #pragma unroll
  for(int j=0;j<8;j++){ aq[j]=0.f; ap[j]=0.f; }
  #pragma unroll 4
  for(int c=0;c<CIN;c++){
    float xc = xn[c];
    float4 wa0 = *(const float4*)&WT[(size_t)c*COUT + o0];
    float4 wa1 = *(const float4*)&WT[(size_t)c*COUT + o0 + 4];
    float4 wb0 = *(const float4*)&WT[(size_t)(CIN+c)*COUT + o0];
    float4 wb1 = *(const float4*)&WT[(size_t)(CIN+c)*COUT + o0 + 4];
    aq[0]=fmaf(xc,wa0.x,aq[0]); aq[1]=fmaf(xc,wa0.y,aq[1]); aq[2]=fmaf(xc,wa0.z,aq[2]); aq[3]=fmaf(xc,wa0.w,aq[3]);
    aq[4]=fmaf(xc,wa1.x,aq[4]); aq[5]=fmaf(xc,wa1.y,aq[5]); aq[6]=fmaf(xc,wa1.z,aq[6]); aq[7]=fmaf(xc,wa1.w,aq[7]);
    ap[0]=fmaf(xc,wb0.x,ap[0]); ap[1]=fmaf(xc,wb0.y,ap[1]); ap[2]=fmaf(xc,wb0.z,ap[2]); ap[3]=fmaf(xc,wb0.w,ap[3]);
    ap[4]=fmaf(xc,wb1.x,ap[4]); ap[5]=fmaf(xc,wb1.y,ap[5]); ap[6]=fmaf(xc,wb1.z,ap[6]); ap[7]=fmaf(xc,wb1.w,ap[7]);
  }
  float* qp = q  + (size_t)row*64 + (o0-cb);
  float* bp = bs + (size_t)row*64 + (o0-cb);
  *(float4*)qp     = make_float4(aq[0],aq[1],aq[2],aq[3]);
  *(float4*)(qp+4) = make_float4(aq[4],aq[5],aq[6],aq[7]);
  *(float4*)bp     = make_float4(ap[0]-aq[0],ap[1]-aq[1],ap[2]-aq[2],ap[3]-aq[3]);
  *(float4*)(bp+4) = make_float4(ap[4]-aq[4],ap[5]-aq[5],ap[6]-aq[6],ap[7]-aq[7]);
}

// full-width qp (big path): q/bs width COUT, single dispatch
template<int CIN, int COUT>
__launch_bounds__(256) __global__ void qpT_full_k(const float* __restrict__ X, const float* __restrict__ WT,
                                                  float* __restrict__ q, float* __restrict__ bs){
  constexpr int OG = COUT/8;
  const int t   = blockIdx.x*256 + threadIdx.x;   // BN*OG
  const int row = t / OG;
  const int o0  = (t % OG) * 8;
  float xn[CIN];
  #pragma unroll
  for(int c=0;c<CIN;c+=4){ float4 v = *(const float4*)(X + (size_t)row*CIN + c);
    xn[c]=v.x; xn[c+1]=v.y; xn[c+2]=v.z; xn[c+3]=v.w; }
  float aq[8], ap[8];
  #pragma unroll
  for(int j=0;j<8;j++){ aq[j]=0.f; ap[j]=0.f; }
  #pragma unroll 4
  for(int c=0;c<CIN;c++){
    float xc = xn[c];
    float4 wa0 = *(const float4*)&WT[(size_t)c*COUT + o0];
    float4 wa1 = *(const float4*)&WT[(size_t)c*COUT + o0 + 4];
    float4 wb0 = *(const float4*)&WT[(size_t)(CIN+c)*COUT + o0];
    float4 wb1 = *(const float4*)&WT[(size_t)(CIN+c)*COUT + o0 + 4];
    aq[0]=fmaf(xc,wa0.x,aq[0]); aq[1]=fmaf(xc,wa0.y,aq[1]); aq[2]=fmaf(xc,wa0.z,aq[2]); aq[3]=fmaf(xc,wa0.w,aq[3]);
    aq[4]=fmaf(xc,wa1.x,aq[4]); aq[5]=fmaf(xc,wa1.y,aq[5]); aq[6]=fmaf(xc,wa1.z,aq[6]); aq[7]=fmaf(xc,wa1.w,aq[7]);
    ap[0]=fmaf(xc,wb0.x,ap[0]); ap[1]=fmaf(xc,wb0.y,ap[1]); ap[2]=fmaf(xc,wb0.z,ap[2]); ap[3]=fmaf(xc,wb0.w,ap[3]);
    ap[4]=fmaf(xc,wb1.x,ap[4]); ap[5]=fmaf(xc,wb1.y,ap[5]); ap[6]=fmaf(xc,wb1.z,ap[6]); ap[7]=fmaf(xc,wb1.w,ap[7]);
  }
  float* qp = q  + (size_t)row*COUT + o0;
  float* bp = bs + (size_t)row*COUT + o0;
  *(float4*)qp     = make_float4(aq[0],aq[1],aq[2],aq[3]);
  *(float4*)(qp+4) = make_float4(aq[4],aq[5],aq[6],aq[7]);
  *(float4*)bp     = make_float4(ap[0]-aq[0],ap[1]-aq[1],ap[2]-aq[2],ap[3]-aq[3]);
  *(float4*)(bp+4) = make_float4(ap[4]-aq[4],ap[5]-aq[5],ap[6]-aq[6],ap[7]-aq[7]);
}

// chunked (fallback) gather: q width 64, out width CFULL at col offset cb
template<int CFULL>
__launch_bounds__(256) __global__ void gather_chunk_k(const float* q, const float* bs, const int* idx,
    const float* g, const float* bb, int cb, float* out){
  const int t  = blockIdx.x*256 + threadIdx.x;
  const int o  = t & 63;
  const int bn = t >> 6;
  const int b  = bn >> 11;
  const int* id = idx + (size_t)bn*KK;
  float base = bs[t];
  float mx = -INFINITY, mn = INFINITY;
  #pragma unroll
  for(int k=0;k<KK;k++){
    int ik = id[k];
    float v = q[((size_t)((b<<11) + ik))*64 + o];
    mx = fmaxf(mx, v); mn = fminf(mn, v);
  }
  float a  = g[cb+o] * RSQ;
  float bo = bb[cb+o];
  out[(size_t)bn*CFULL + cb + o] = lrelu((a >= 0.f ? a*(mx+base) : a*(mn+base)) + bo);
}

// full-width gather (big path): q/bs/out width CFULL
template<int CFULL>
__launch_bounds__(256) __global__ void gather_full_k(const float* q, const float* bs, const int* idx,
    const float* g, const float* bb, float* out){
  const int t  = blockIdx.x*256 + threadIdx.x;   // BN*CFULL
  const int o  = t % CFULL;
  const int bn = t / CFULL;
  const int b  = bn >> 11;
  const int* id = idx + (size_t)bn*KK;
  float base = bs[t];
  float mx = -INFINITY, mn = INFINITY;
  #pragma unroll
  for(int k=0;k<KK;k++){
    int ik = id[k];
    float v = q[((size_t)((b<<11) + ik))*CFULL + o];
    mx = fmaxf(mx, v); mn = fminf(mn, v);
  }
  float a  = g[o] * RSQ;
  float bo = bb[o];
  out[(size_t)bn*CFULL + o] = lrelu((a >= 0.f ? a*(mx+base) : a*(mn+base)) + bo);
}

// ---------------- head: GEMM-tiled cat x W5T with fused per-column max/min ----------------
// 128 rows x 128 cols per block, 8x8 micro-tile (gemm_dist structure). A = cat gathered
// per 16-c chunk (chunks never straddle x1/x2/x3/x4 boundaries). Epilogue: col max/min
// over 8 rows in regs, then shfl_xor over tn (lane bits 0..3), then atomicMax/Min.
__launch_bounds__(256) __global__ void w5gemm_k(const float* __restrict__ x1, const float* __restrict__ x2,
    const float* __restrict__ x3, const float* __restrict__ x4,
    const float* __restrict__ W5T, unsigned* mxe, unsigned* mne){
  constexpr int AST = 188;
  __shared__ __align__(16) float a_sh[16*AST];
  __shared__ __align__(16) float b_sh[16*AST];
  const int tid = threadIdx.x;
  const int otile = blockIdx.x*128;     // 4
  const int rtile = blockIdx.y*128;     // 16
  const int b     = blockIdx.z;         // 8
  const int tn = tid & 15, tm = tid >> 4;
  const size_t row0 = (size_t)b*NN + rtile;
  float acc[8][8];
  #pragma unroll
  for(int i=0;i<8;i++){
    #pragma unroll
    for(int j=0;j<8;j++) acc[i][j]=0.f;
  }
  for(int cc=0; cc<512; cc+=16){
    const float* src; int stride, coff;
    if(cc<64)      { src=x1; stride=64;  coff=cc; }
    else if(cc<128){ src=x2; stride=64;  coff=cc-64; }
    else if(cc<256){ src=x3; stride=128; coff=cc-128; }
    else           { src=x4; stride=256; coff=cc-256; }
    __syncthreads();
    #pragma unroll
    for(int s=0;s<2;s++){
      int ii = tid + 256*s;
      { int r = ii>>2, qq = ii&3;
        int pr = r + 4*(r>>3);
        float4 va = *(const float4*)&src[(row0 + r)*stride + coff + 4*qq];
        a_sh[(4*qq+0)*AST + pr]=va.x; a_sh[(4*qq+1)*AST + pr]=va.y;
        a_sh[(4*qq+2)*AST + pr]=va.z; a_sh[(4*qq+3)*AST + pr]=va.w; }
      { int cl = ii>>5, o4 = ii&31;
        float4 vb = *(const float4*)&W5T[(size_t)(cc+cl)*512 + otile + 4*o4];
        *(float4*)&b_sh[cl*AST + 4*o4 + 4*(o4>>1)] = vb; }
    }
    __syncthreads();
    #pragma unroll
    for(int c=0;c<16;c++){
      float4 A0 = *(const float4*)&a_sh[c*AST + 12*tn];
      float4 A1 = *(const float4*)&a_sh[c*AST + 12*tn + 4];
      float4 B0 = *(const float4*)&b_sh[c*AST + 12*tm];
      float4 B1 = *(const float4*)&b_sh[c*AST + 12*tm + 4];
      float b0v=B0.x,b1v=B0.y,b2v=B0.z,b3v=B0.w,b4v=B1.x,b5v=B1.y,b6v=B1.z,b7v=B1.w;
      float a;
      a=A0.x; FMA_ROW(0)
      a=A0.y; FMA_ROW(1)
      a=A0.z; FMA_ROW(2)
      a=A0.w; FMA_ROW(3)
      a=A1.x; FMA_ROW(4)
      a=A1.y; FMA_ROW(5)
      a=A1.z; FMA_ROW(6)
      a=A1.w; FMA_ROW(7)
    }
  }
  #pragma unroll
  for(int j=0;j<8;j++){
    float M=-INFINITY, m=INFINITY;
    #pragma unroll
    for(int i=0;i<8;i++){ M=fmaxf(M,acc[i][j]); m=fminf(m,acc[i][j]); }
    #pragma unroll
    for(int d=1; d<16; d<<=1){
      M = fmaxf(M, __shfl_xor(M, d));
      m = fminf(m, __shfl_xor(m, d));
    }
    if(tn == 0){
      int o = otile + tm*8 + j;
      atomicMax(&mxe[b*512+o], encf(M));
      atomicMin(&mne[b*512+o], encf(m));
    }
  }
}

__launch_bounds__(256) __global__ void final_k(const unsigned* mxe, const unsigned* mne,
    const float* g5, const float* b5, const float* Wemb, float* out){
  const int b = blockIdx.x, t = threadIdx.x;
  __shared__ float h[512];
  for(int o=t; o<512; o+=256){
    float mx = decf(mxe[b*512+o]);
    float mn = decf(mne[b*512+o]);
    float a  = g5[o] * RSQ;
    float bo = b5[o];
    float hv = lrelu((a >= 0.f ? a*mx : a*mn) + bo);
    h[o] = hv;
    out[b*512+o] = hv;
  }
  __syncthreads();
  const float* wr = Wemb + (size_t)t*512;
  float s = 0.f;
  for(int o=0;o<512;o+=4){
    float4 w4 = *(const float4*)(wr+o);
    s = fmaf(h[o],w4.x, fmaf(h[o+1],w4.y, fmaf(h[o+2],w4.z, fmaf(h[o+3],w4.w, s))));
  }
  out[4096 + b*256 + t] = s;
}

// ---------------- launch ----------------
extern "C" void kernel_launch(void* const* d_in, const int* in_sizes, int n_in,
                              void* d_out, int out_size, void* d_ws, size_t ws_size,
                              hipStream_t stream) {
  if (ws_size < WS_END * sizeof(float)) return;
  const bool big = ws_size >= WS_BIG_END * sizeof(float);   // deterministic per call

  const float* x0   = (const float*)d_in[0];
  const float* W1   = (const float*)d_in[1];
  const float* g1   = (const float*)d_in[2];
  const float* b1   = (const float*)d_in[3];
  const float* g2   = (const float*)d_in[5];
  const float* b2   = (const float*)d_in[6];
  const float* g3   = (const float*)d_in[8];
  const float* b3   = (const float*)d_in[9];
  const float* g4   = (const float*)d_in[11];
  const float* b4   = (const float*)d_in[12];
  const float* W2   = (const float*)d_in[4];
  const float* W3   = (const float*)d_in[7];
  const float* W4   = (const float*)d_in[10];
  const float* W5   = (const float*)d_in[13];
  const float* g5   = (const float*)d_in[14];
  const float* b5   = (const float*)d_in[15];
  const float* Wemb = (const float*)d_in[16];

  float* ws = (float*)d_ws;
  float* xx = ws + OFF_XX;
  float* x1 = ws + OFF_X1;  float* x2 = ws + OFF_X2;
  float* x3 = ws + OFF_X3;  float* x4 = ws + OFF_X4;
  float* qS  = ws + OFF_SC;
  float* bsS = ws + OFF_SC + (size_t)BN*64;
  int*   id = (int*)(ws + OFF_ID);
  float* W5Tf = ws + OFF_W5T;
  unsigned* mxe = (unsigned*)(ws + OFF_MX);
  unsigned* mne = (unsigned*)(ws + OFF_MN);
  float* WT2 = ws + OFF_WT2;
  float* WT3 = ws + OFF_WT3;
  float* WT4 = ws + OFF_WT4;
  float* distD = ws + OFF_X3;   // fallback dual-batch
  float* distS = ws + OFF_X4;   // fallback single-batch
  float* distB = ws + OFF_BIG;  // big: 8-batch dist, then reused as full q/bs
  float* out = (float*)d_out;

  prep_k<<<1024,256,0,stream>>>(W5, W2, W3, W4, W5Tf, WT2, WT3, WT4, mxe, mne);

  // layer 1 (3 -> 64): sqnorm fused into sel3
  sel3_k<<<BN*64/256,256,0,stream>>>(x0, id);
  qp3_k<<<BN*8/256,256,0,stream>>>(x0, W1, qS, bsS);
  gather_full_k<64><<<BN*64/256,256,0,stream>>>(qS, bsS, id, g1, b1, x1);

  if(big){
    float* qB  = distB;                       // reuse dist region post-sel
    // layer 2
    sqnorm_k<64><<<BN/256,256,0,stream>>>(x1, xx);
    gemm_dist_k<64><<<dim3(16,16,8),256,0,stream>>>(x1, xx, distB, 0);
    sel_k<<<(8*NN)/4,256,0,stream>>>(distB, id, 0, 8*NN);
    qpT_full_k<64,64><<<BN*8/256,256,0,stream>>>(x1, WT2, qB, qB + (size_t)BN*64);
    gather_full_k<64><<<BN*64/256,256,0,stream>>>(qB, qB + (size_t)BN*64, id, g2, b2, x2);
    // layer 3
    sqnorm_k<64><<<BN/256,256,0,stream>>>(x2, xx);
    gemm_dist_k<64><<<dim3(16,16,8),256,0,stream>>>(x2, xx, distB, 0);
    sel_k<<<(8*NN)/4,256,0,stream>>>(distB, id, 0, 8*NN);
    qpT_full_k<64,128><<<BN*16/256,256,0,stream>>>(x2, WT3, qB, qB + (size_t)BN*128);
    gather_full_k<128><<<BN*128/256,256,0,stream>>>(qB, qB + (size_t)BN*128, id, g3, b3, x3);
    // layer 4
    sqnorm_k<128><<<BN/256,256,0,stream>>>(x3, xx);
    gemm_dist_k<128><<<dim3(16,16,8),256,0,stream>>>(x3, xx, distB, 0);
    sel_k<<<(8*NN)/4,256,0,stream>>>(distB, id, 0, 8*NN);
    qpT_full_k<128,256><<<BN*32/256,256,0,stream>>>(x3, WT4, qB, qB + (size_t)BN*256);
    gather_full_k<256><<<BN*256/256,256,0,stream>>>(qB, qB + (size_t)BN*256, id, g4, b4, x4);
  } else {
    // fallback: chunked (R12 structure)
    sqnorm_k<64><<<BN/256,256,0,stream>>>(x1, xx);
    for(int r=0;r<4;r++){
      gemm_dist_k<64><<<dim3(16,16,2),256,0,stream>>>(x1, xx, distD, 2*r);
      sel_k<<<(2*NN)/4,256,0,stream>>>(distD, id, 2*r, 2*NN);
    }
    qp64T_k<64,64><<<BN*8/256,256,0,stream>>>(x1, WT2, 0, qS, bsS);
    gather_chunk_k<64><<<BN*64/256,256,0,stream>>>(qS, bsS, id, g2, b2, 0, x2);

    sqnorm_k<64><<<BN/256,256,0,stream>>>(x2, xx);
    for(int r=0;r<4;r++){
      gemm_dist_k<64><<<dim3(16,16,2),256,0,stream>>>(x2, xx, distD, 2*r);
      sel_k<<<(2*NN)/4,256,0,stream>>>(distD, id, 2*r, 2*NN);
    }
    for(int cb=0; cb<128; cb+=64){
      qp64T_k<64,128><<<BN*8/256,256,0,stream>>>(x2, WT3, cb, qS, bsS);
      gather_chunk_k<128><<<BN*64/256,256,0,stream>>>(qS, bsS, id, g3, b3, cb, x3);
    }

    sqnorm_k<128><<<BN/256,256,0,stream>>>(x3, xx);
    for(int r=0;r<8;r++){
      gemm_dist_k<128><<<dim3(16,16,1),256,0,stream>>>(x3, xx, distS, r);
      sel_k<<<NN/4,256,0,stream>>>(distS, id, r, NN);
    }
    for(int cb=0; cb<256; cb+=64){
      qp64T_k<128,256><<<BN*8/256,256,0,stream>>>(x3, WT4, cb, qS, bsS);
      gather_chunk_k<256><<<BN*64/256,256,0,stream>>>(qS, bsS, id, g4, b4, cb, x4);
    }
  }

  // head
  w5gemm_k<<<dim3(4,16,8),256,0,stream>>>(x1, x2, x3, x4, W5Tf, mxe, mne);
  final_k<<<BB,256,0,stream>>>(mxe, mne, g5, b5, Wemb, out);
}

// Round 14
// 954.359 us; speedup vs baseline: 1.3232x; 1.3232x over previous
//
#include <hip/hip_runtime.h>
#include <hip/hip_bf16.h>

#define BB 8
#define NN 2048
#define KK 20
#define BN (BB*NN)
#define RSQ 0.99999500003749969f   // 1/sqrt(1+1e-5)

// ---------------- workspace layout (float-slot units), 44.7 MiB baseline ----------------
constexpr size_t OFF_XX  = 0;                          // BN
constexpr size_t OFF_X1  = OFF_XX  + BN;               // BN*64
constexpr size_t OFF_X2  = OFF_X1  + (size_t)BN*64;    // BN*64
constexpr size_t OFF_X3  = OFF_X2  + (size_t)BN*64;    // BN*128
constexpr size_t OFF_X4  = OFF_X3  + (size_t)BN*128;   // BN*256
constexpr size_t OFF_SC  = OFF_X4  + (size_t)BN*256;   // BN*160 (L1 qp + fallback chunked qp)
constexpr size_t OFF_ID  = OFF_SC  + (size_t)BN*160;   // int BN*20
constexpr size_t OFF_W5T = OFF_ID  + (size_t)BN*20;    // 512*512
constexpr size_t OFF_MX  = OFF_W5T + 512*512;
constexpr size_t OFF_MN  = OFF_MX  + BB*512;
constexpr size_t OFF_WT2 = OFF_MN  + BB*512;           // cat [64][128]
constexpr size_t OFF_WT3 = OFF_WT2 + 8192;             // cat [64][256]
constexpr size_t OFF_WT4 = OFF_WT3 + 16384;            // cat [128][512]
constexpr size_t WS_END  = OFF_WT4 + 65536;            // 11,714,560 floats
// big region (probed at runtime): 8-batch dist; reused as full qp buffer post-sel
constexpr size_t OFF_BIG = WS_END;
constexpr size_t WS_BIG_END = OFF_BIG + (size_t)BB*NN*NN;   // 172.7 MiB
static_assert(OFF_ID - OFF_X3 >= (size_t)4096*2048, "fallback dual dist fits");

__device__ inline unsigned encf(float f){ unsigned u=__float_as_uint(f); return (u&0x80000000u)? ~u : (u|0x80000000u); }
__device__ inline float decf(unsigned e){ unsigned u=(e&0x80000000u)? (e&0x7fffffffu) : ~e; return __uint_as_float(u); }
__device__ inline float lrelu(float h){ return h>=0.f ? h : 0.2f*h; }

// ---------------- prep: cat-transposed weights [c][q-cols|p-cols] + W5T + enc ----------------
__global__ void prep_k(const float* W5, const float* W2, const float* W3, const float* W4,
                       float* W5T, float* WT2, float* WT3, float* WT4,
                       unsigned* mx, unsigned* mn){
  int i = blockIdx.x*256 + threadIdx.x;     // 262144
  { int o = i>>9, c = i&511; W5T[c*512+o] = W5[i]; }
  if(i < 65536){ int c = i>>9, o = i&511;   // W4: [256][256] -> cat [128][512]
    WT4[i] = (o<256) ? W4[(size_t)o*256 + c] : W4[(size_t)(o-256)*256 + 128 + c]; }
  if(i < 16384){ int c = i>>8, o = i&255;   // W3: [128][128] -> cat [64][256]
    WT3[i] = (o<128) ? W3[(size_t)o*128 + c] : W3[(size_t)(o-128)*128 + 64 + c]; }
  if(i <  8192){ int c = i>>7, o = i&127;   // W2: [64][128] -> cat [64][128]
    WT2[i] = (o<64) ? W2[(size_t)o*128 + c] : W2[(size_t)(o-64)*128 + 64 + c]; }
  if(i <  4096){ mx[i] = 0x007FFFFFu; mn[i] = 0xFF800000u; }
}

// ---------------- KNN ----------------
template<int C>
__launch_bounds__(256) __global__ void sqnorm_k(const float* X, float* xx){
  int i = blockIdx.x*256 + threadIdx.x;   // BN
  const float* r = X + (size_t)i*C;
  float s = 0.f;
  #pragma unroll
  for(int c=0;c<C;c++) s = fmaf(r[c], r[c], s);
  xx[i] = s;
}

#define FMA_ROW(I) \
  acc[I][0]=fmaf(a,b0v,acc[I][0]); acc[I][1]=fmaf(a,b1v,acc[I][1]); \
  acc[I][2]=fmaf(a,b2v,acc[I][2]); acc[I][3]=fmaf(a,b3v,acc[I][3]); \
  acc[I][4]=fmaf(a,b4v,acc[I][4]); acc[I][5]=fmaf(a,b5v,acc[I][5]); \
  acc[I][6]=fmaf(a,b6v,acc[I][6]); acc[I][7]=fmaf(a,b7v,acc[I][7]);

template<int C>
__launch_bounds__(256) __global__ void gemm_dist_k(const float* __restrict__ X, const float* __restrict__ xx,
                                                   float* __restrict__ dist, int b0){
  constexpr int AST = 188;
  __shared__ __align__(16) float a_sh[16*AST];
  __shared__ __align__(16) float b_sh[16*AST];
  __shared__ float sxn[128], sxm[128];
  const int tid = threadIdx.x;
  const int b   = b0 + blockIdx.z;
  const int mtile = blockIdx.x*128;
  const int ntile = blockIdx.y*128;
  const int tn = tid & 15, tm = tid >> 4;
  const float* Xb  = X  + (size_t)b*NN*C;
  const float* xxb = xx + (size_t)b*NN;
  if(tid < 128) sxn[tid] = xxb[ntile + tid];
  else          sxm[tid-128] = xxb[mtile + tid-128];
  float acc[8][8];
  #pragma unroll
  for(int i=0;i<8;i++){
    #pragma unroll
    for(int j=0;j<8;j++) acc[i][j]=0.f;
  }
  for(int cc=0; cc<C; cc+=16){
    __syncthreads();
    #pragma unroll
    for(int s=0;s<2;s++){
      int ii = tid + 256*s; int r = ii>>2, q = ii&3;
      int pr = r + 4*(r>>3);
      float4 va = *(const float4*)&Xb[(size_t)(ntile + r)*C + cc + 4*q];
      a_sh[(4*q+0)*AST + pr]=va.x; a_sh[(4*q+1)*AST + pr]=va.y;
      a_sh[(4*q+2)*AST + pr]=va.z; a_sh[(4*q+3)*AST + pr]=va.w;
      float4 vb = *(const float4*)&Xb[(size_t)(mtile + r)*C + cc + 4*q];
      b_sh[(4*q+0)*AST + pr]=vb.x; b_sh[(4*q+1)*AST + pr]=vb.y;
      b_sh[(4*q+2)*AST + pr]=vb.z; b_sh[(4*q+3)*AST + pr]=vb.w;
    }
    __syncthreads();
    #pragma unroll
    for(int c=0;c<16;c++){
      float4 A0 = *(const float4*)&a_sh[c*AST + 12*tn];
      float4 A1 = *(const float4*)&a_sh[c*AST + 12*tn + 4];
      float4 B0 = *(const float4*)&b_sh[c*AST + 12*tm];
      float4 B1 = *(const float4*)&b_sh[c*AST + 12*tm + 4];
      float b0v=B0.x,b1v=B0.y,b2v=B0.z,b3v=B0.w,b4v=B1.x,b5v=B1.y,b6v=B1.z,b7v=B1.w;
      float a;
      a=A0.x; FMA_ROW(0)
      a=A0.y; FMA_ROW(1)
      a=A0.z; FMA_ROW(2)
      a=A0.w; FMA_ROW(3)
      a=A1.x; FMA_ROW(4)
      a=A1.y; FMA_ROW(5)
      a=A1.z; FMA_ROW(6)
      a=A1.w; FMA_ROW(7)
    }
  }
  float xnr[8], xmr[8];
  #pragma unroll
  for(int i=0;i<8;i++){ xnr[i]=sxn[tn*8+i]; xmr[i]=sxm[tm*8+i]; }
  const size_t rowb = (size_t)blockIdx.z*NN + ntile + tn*8;
  #pragma unroll
  for(int i=0;i<8;i++){
    float4 w0, w1;
    w0.x=(2.f*acc[i][0]-xnr[i])-xmr[0]; w0.y=(2.f*acc[i][1]-xnr[i])-xmr[1];
    w0.z=(2.f*acc[i][2]-xnr[i])-xmr[2]; w0.w=(2.f*acc[i][3]-xnr[i])-xmr[3];
    w1.x=(2.f*acc[i][4]-xnr[i])-xmr[4]; w1.y=(2.f*acc[i][5]-xnr[i])-xmr[5];
    w1.z=(2.f*acc[i][6]-xnr[i])-xmr[6]; w1.w=(2.f*acc[i][7]-xnr[i])-xmr[7];
    float* dp = dist + (rowb + i)*NN + mtile + tm*8;
    *(float4*)dp = w0;
    *(float4*)(dp+4) = w1;
  }
}

// Wave-cooperative top-20 (sorted in lanes 0..19)
__launch_bounds__(256) __global__ void sel_k(const float* __restrict__ dist, int* __restrict__ id,
                                             int b0, int nrows){
  const int w = (blockIdx.x*256 + threadIdx.x) >> 6;
  const int lane = threadIdx.x & 63;
  if(w >= nrows) return;
  const float* dr = dist + (size_t)w*NN;
  float lv = -INFINITY; int li = 0;
  float theta = -INFINITY;
  for(int ms=0; ms<NN; ms+=64){
    float cand = dr[ms + lane];
    unsigned long long bal = __ballot(cand > theta);
    while(bal){
      int bpos = __ffsll((unsigned long long)bal) - 1;
      bal &= bal - 1;
      float cv = __shfl(cand, bpos);
      if(cv > theta){
        int ci = ms + bpos;
        unsigned long long mge = __ballot(lv >= cv);
        int pos = __popcll(mge);
        float upv = __shfl_up(lv, 1);
        int   upi = __shfl_up(li, 1);
        bool shift = (lane > pos) && (lane < KK);
        lv = (lane == pos) ? cv : (shift ? upv : lv);
        li = (lane == pos) ? ci : (shift ? upi : li);
        theta = __shfl(lv, KK-1);
      }
    }
  }
  if(lane < KK) id[((size_t)b0*NN + w)*KK + lane] = li;
}

// L1 fused: inline C=3 distances + inline sqnorm
__launch_bounds__(256) __global__ void sel3_k(const float* __restrict__ X, int* __restrict__ id){
  const int gw = (blockIdx.x*256 + threadIdx.x) >> 6;
  const int lane = threadIdx.x & 63;
  const int b = gw >> 11, n = gw & 2047;
  const float* Xb  = X + (size_t)b*NN*3;
  const float x0v = Xb[n*3], x1v = Xb[n*3+1], x2v = Xb[n*3+2];
  float xxn = 0.f;
  xxn = fmaf(x0v, x0v, xxn); xxn = fmaf(x1v, x1v, xxn); xxn = fmaf(x2v, x2v, xxn);
  float lv = -INFINITY; int li = 0;
  float theta = -INFINITY;
  for(int ms=0; ms<NN; ms+=64){
    int m = ms + lane;
    float m0 = Xb[m*3+0], m1 = Xb[m*3+1], m2 = Xb[m*3+2];
    float s = 0.f;
    s = fmaf(x0v, m0, s); s = fmaf(x1v, m1, s); s = fmaf(x2v, m2, s);
    float xxm = 0.f;
    xxm = fmaf(m0, m0, xxm); xxm = fmaf(m1, m1, xxm); xxm = fmaf(m2, m2, xxm);
    float cand = (2.f*s - xxn) - xxm;
    unsigned long long bal = __ballot(cand > theta);
    while(bal){
      int bpos = __ffsll((unsigned long long)bal) - 1;
      bal &= bal - 1;
      float cv = __shfl(cand, bpos);
      if(cv > theta){
        int ci = ms + bpos;
        unsigned long long mge = __ballot(lv >= cv);
        int pos = __popcll(mge);
        float upv = __shfl_up(lv, 1);
        int   upi = __shfl_up(li, 1);
        bool shift = (lane > pos) && (lane < KK);
        lv = (lane == pos) ? cv : (shift ? upv : lv);
        li = (lane == pos) ? ci : (shift ? upi : li);
        theta = __shfl(lv, KK-1);
      }
    }
  }
  if(lane < KK) id[(size_t)gw*KK + lane] = li;
}

// ---------------- qp ----------------
// L1: writes interleaved qp[row][128]: q at 0..63, p at 64..127
__launch_bounds__(256) __global__ void qp3_k(const float* X, const float* W, float* qp){
  const int t   = blockIdx.x*256 + threadIdx.x;
  const int row = t >> 3;
  const int c0  = (t & 7) * 8;
  float xn[3];
  #pragma unroll
  for(int c=0;c<3;c++) xn[c] = X[(size_t)row*3 + c];
  for(int oi=c0; oi<c0+8; oi++){
    const float* w = W + (size_t)oi*6;
    float aq=0.f, ap=0.f;
    #pragma unroll
    for(int c=0;c<3;c++){ aq = fmaf(xn[c], w[c], aq); ap = fmaf(xn[c], w[3+c], ap); }
    qp[(size_t)row*128 + oi]      = aq;
    qp[(size_t)row*128 + 64 + oi] = ap;
  }
}

// Tiled qp GEMM (big path): C[BN x W2C] = X[BN x CIN] * WTcat[CIN x W2C].
// Clone of gemm_dist structure (proven conflict-free). W2C = 2*COUT.
template<int CIN, int W2C>
__launch_bounds__(256) __global__ void qp_gemm_k(const float* __restrict__ X, const float* __restrict__ WT,
                                                 float* __restrict__ qp){
  constexpr int AST = 188;
  __shared__ __align__(16) float a_sh[16*AST];
  __shared__ __align__(16) float b_sh[16*AST];
  const int tid = threadIdx.x;
  const int otile = blockIdx.x*128;
  const int rtile = blockIdx.y*128;
  const int tn = tid & 15, tm = tid >> 4;
  float acc[8][8];
  #pragma unroll
  for(int i=0;i<8;i++){
    #pragma unroll
    for(int j=0;j<8;j++) acc[i][j]=0.f;
  }
  for(int cc=0; cc<CIN; cc+=16){
    __syncthreads();
    #pragma unroll
    for(int s=0;s<2;s++){
      int ii = tid + 256*s;
      { int r = ii>>2, qq = ii&3;
        int pr = r + 4*(r>>3);
        float4 va = *(const float4*)&X[(size_t)(rtile + r)*CIN + cc + 4*qq];
        a_sh[(4*qq+0)*AST + pr]=va.x; a_sh[(4*qq+1)*AST + pr]=va.y;
        a_sh[(4*qq+2)*AST + pr]=va.z; a_sh[(4*qq+3)*AST + pr]=va.w; }
      { int cl = ii>>5, o4 = ii&31;
        float4 vb = *(const float4*)&WT[(size_t)(cc+cl)*W2C + otile + 4*o4];
        *(float4*)&b_sh[cl*AST + 4*o4 + 4*(o4>>1)] = vb; }
    }
    __syncthreads();
    #pragma unroll
    for(int c=0;c<16;c++){
      float4 A0 = *(const float4*)&a_sh[c*AST + 12*tn];
      float4 A1 = *(const float4*)&a_sh[c*AST + 12*tn + 4];
      float4 B0 = *(const float4*)&b_sh[c*AST + 12*tm];
      float4 B1 = *(const float4*)&b_sh[c*AST + 12*tm + 4];
      float b0v=B0.x,b1v=B0.y,b2v=B0.z,b3v=B0.w,b4v=B1.x,b5v=B1.y,b6v=B1.z,b7v=B1.w;
      float a;
      a=A0.x; FMA_ROW(0)
      a=A0.y; FMA_ROW(1)
      a=A0.z; FMA_ROW(2)
      a=A0.w; FMA_ROW(3)
      a=A1.x; FMA_ROW(4)
      a=A1.y; FMA_ROW(5)
      a=A1.z; FMA_ROW(6)
      a=A1.w; FMA_ROW(7)
    }
  }
  #pragma unroll
  for(int i=0;i<8;i++){
    float* dp = qp + (size_t)(rtile + tn*8 + i)*W2C + otile + tm*8;
    *(float4*)dp     = make_float4(acc[i][0],acc[i][1],acc[i][2],acc[i][3]);
    *(float4*)(dp+4) = make_float4(acc[i][4],acc[i][5],acc[i][6],acc[i][7]);
  }
}

// Gather from interleaved qp[row][2*COUT] (q | p); base = p - q computed here (bit-exact).
template<int COUT>
__launch_bounds__(256) __global__ void gather_qp_k(const float* __restrict__ qp, const int* __restrict__ idx,
    const float* g, const float* bb, float* out){
  const int t  = blockIdx.x*256 + threadIdx.x;   // BN*COUT
  const int o  = t % COUT;
  const int bn = t / COUT;
  const int b  = bn >> 11;
  const int* id = idx + (size_t)bn*KK;
  float qv = qp[(size_t)bn*(2*COUT) + o];
  float pv = qp[(size_t)bn*(2*COUT) + COUT + o];
  float base = pv - qv;
  float mx = -INFINITY, mn = INFINITY;
  #pragma unroll
  for(int k=0;k<KK;k++){
    int ik = id[k];
    float v = qp[((size_t)((b<<11) + ik))*(2*COUT) + o];
    mx = fmaxf(mx, v); mn = fminf(mn, v);
  }
  float a  = g[o] * RSQ;
  float bo = bb[o];
  out[(size_t)bn*COUT + o] = lrelu((a >= 0.f ? a*(mx+base) : a*(mn+base)) + bo);
}

// ---- fallback chunked qp (cat weight layout) + chunked gather ----
template<int CIN, int COUT>
__launch_bounds__(256) __global__ void qp64T_k(const float* __restrict__ X, const float* __restrict__ WT,
                                               int cb, float* __restrict__ q, float* __restrict__ bs){
  const int t   = blockIdx.x*256 + threadIdx.x;
  const int row = t >> 3;
  const int o0  = cb + (t & 7) * 8;
  float xn[CIN];
  #pragma unroll
  for(int c=0;c<CIN;c+=4){ float4 v = *(const float4*)(X + (size_t)row*CIN + c);
    xn[c]=v.x; xn[c+1]=v.y; xn[c+2]=v.z; xn[c+3]=v.w; }
  float aq[8], ap[8];
  #pragma unroll
  for(int j=0;j<8;j++){ aq[j]=0.f; ap[j]=0.f; }
  #pragma unroll 4
  for(int c=0;c<CIN;c++){
    float xc = xn[c];
    float4 wa0 = *(const float4*)&WT[(size_t)c*(2*COUT) + o0];
    float4 wa1 = *(const float4*)&WT[(size_t)c*(2*COUT) + o0 + 4];
    float4 wb0 = *(const float4*)&WT[(size_t)c*(2*COUT) + COUT + o0];
    float4 wb1 = *(const float4*)&WT[(size_t)c*(2*COUT) + COUT + o0 + 4];
    aq[0]=fmaf(xc,wa0.x,aq[0]); aq[1]=fmaf(xc,wa0.y,aq[1]); aq[2]=fmaf(xc,wa0.z,aq[2]); aq[3]=fmaf(xc,wa0.w,aq[3]);
    aq[4]=fmaf(xc,wa1.x,aq[4]); aq[5]=fmaf(xc,wa1.y,aq[5]); aq[6]=fmaf(xc,wa1.z,aq[6]); aq[7]=fmaf(xc,wa1.w,aq[7]);
    ap[0]=fmaf(xc,wb0.x,ap[0]); ap[1]=fmaf(xc,wb0.y,ap[1]); ap[2]=fmaf(xc,wb0.z,ap[2]); ap[3]=fmaf(xc,wb0.w,ap[3]);
    ap[4]=fmaf(xc,wb1.x,ap[4]); ap[5]=fmaf(xc,wb1.y,ap[5]); ap[6]=fmaf(xc,wb1.z,ap[6]); ap[7]=fmaf(xc,wb1.w,ap[7]);
  }
  float* qpp = q  + (size_t)row*64 + (o0-cb);
  float* bpp = bs + (size_t)row*64 + (o0-cb);
  *(float4*)qpp     = make_float4(aq[0],aq[1],aq[2],aq[3]);
  *(float4*)(qpp+4) = make_float4(aq[4],aq[5],aq[6],aq[7]);
  *(float4*)bpp     = make_float4(ap[0]-aq[0],ap[1]-aq[1],ap[2]-aq[2],ap[3]-aq[3]);
  *(float4*)(bpp+4) = make_float4(ap[4]-aq[4],ap[5]-aq[5],ap[6]-aq[6],ap[7]-aq[7]);
}

template<int CFULL>
__launch_bounds__(256) __global__ void gather_chunk_k(const float* q, const float* bs, const int* idx,
    const float* g, const float* bb, int cb, float* out){
  const int t  = blockIdx.x*256 + threadIdx.x;
  const int o  = t & 63;
  const int bn = t >> 6;
  const int b  = bn >> 11;
  const int* id = idx + (size_t)bn*KK;
  float base = bs[t];
  float mx = -INFINITY, mn = INFINITY;
  #pragma unroll
  for(int k=0;k<KK;k++){
    int ik = id[k];
    float v = q[((size_t)((b<<11) + ik))*64 + o];
    mx = fmaxf(mx, v); mn = fminf(mn, v);
  }
  float a  = g[cb+o] * RSQ;
  float bo = bb[cb+o];
  out[(size_t)bn*CFULL + cb + o] = lrelu((a >= 0.f ? a*(mx+base) : a*(mn+base)) + bo);
}

// ---------------- head: GEMM-tiled cat x W5T with fused per-column max/min ----------------
__launch_bounds__(256) __global__ void w5gemm_k(const float* __restrict__ x1, const float* __restrict__ x2,
    const float* __restrict__ x3, const float* __restrict__ x4,
    const float* __restrict__ W5T, unsigned* mxe, unsigned* mne){
  constexpr int AST = 188;
  __shared__ __align__(16) float a_sh[16*AST];
  __shared__ __align__(16) float b_sh[16*AST];
  const int tid = threadIdx.x;
  const int otile = blockIdx.x*128;
  const int rtile = blockIdx.y*128;
  const int b     = blockIdx.z;
  const int tn = tid & 15, tm = tid >> 4;
  const size_t row0 = (size_t)b*NN + rtile;
  float acc[8][8];
  #pragma unroll
  for(int i=0;i<8;i++){
    #pragma unroll
    for(int j=0;j<8;j++) acc[i][j]=0.f;
  }
  for(int cc=0; cc<512; cc+=16){
    const float* src; int stride, coff;
    if(cc<64)      { src=x1; stride=64;  coff=cc; }
    else if(cc<128){ src=x2; stride=64;  coff=cc-64; }
    else if(cc<256){ src=x3; stride=128; coff=cc-128; }
    else           { src=x4; stride=256; coff=cc-256; }
    __syncthreads();
    #pragma unroll
    for(int s=0;s<2;s++){
      int ii = tid + 256*s;
      { int r = ii>>2, qq = ii&3;
        int pr = r + 4*(r>>3);
        float4 va = *(const float4*)&src[(row0 + r)*stride + coff + 4*qq];
        a_sh[(4*qq+0)*AST + pr]=va.x; a_sh[(4*qq+1)*AST + pr]=va.y;
        a_sh[(4*qq+2)*AST + pr]=va.z; a_sh[(4*qq+3)*AST + pr]=va.w; }
      { int cl = ii>>5, o4 = ii&31;
        float4 vb = *(const float4*)&W5T[(size_t)(cc+cl)*512 + otile + 4*o4];
        *(float4*)&b_sh[cl*AST + 4*o4 + 4*(o4>>1)] = vb; }
    }
    __syncthreads();
    #pragma unroll
    for(int c=0;c<16;c++){
      float4 A0 = *(const float4*)&a_sh[c*AST + 12*tn];
      float4 A1 = *(const float4*)&a_sh[c*AST + 12*tn + 4];
      float4 B0 = *(const float4*)&b_sh[c*AST + 12*tm];
      float4 B1 = *(const float4*)&b_sh[c*AST + 12*tm + 4];
      float b0v=B0.x,b1v=B0.y,b2v=B0.z,b3v=B0.w,b4v=B1.x,b5v=B1.y,b6v=B1.z,b7v=B1.w;
      float a;
      a=A0.x; FMA_ROW(0)
      a=A0.y; FMA_ROW(1)
      a=A0.z; FMA_ROW(2)
      a=A0.w; FMA_ROW(3)
      a=A1.x; FMA_ROW(4)
      a=A1.y; FMA_ROW(5)
      a=A1.z; FMA_ROW(6)
      a=A1.w; FMA_ROW(7)
    }
  }
  #pragma unroll
  for(int j=0;j<8;j++){
    float M=-INFINITY, m=INFINITY;
    #pragma unroll
    for(int i=0;i<8;i++){ M=fmaxf(M,acc[i][j]); m=fminf(m,acc[i][j]); }
    #pragma unroll
    for(int d=1; d<16; d<<=1){
      M = fmaxf(M, __shfl_xor(M, d));
      m = fminf(m, __shfl_xor(m, d));
    }
    if(tn == 0){
      int o = otile + tm*8 + j;
      atomicMax(&mxe[b*512+o], encf(M));
      atomicMin(&mne[b*512+o], encf(m));
    }
  }
}

__launch_bounds__(256) __global__ void final_k(const unsigned* mxe, const unsigned* mne,
    const float* g5, const float* b5, const float* Wemb, float* out){
  const int b = blockIdx.x, t = threadIdx.x;
  __shared__ float h[512];
  for(int o=t; o<512; o+=256){
    float mx = decf(mxe[b*512+o]);
    float mn = decf(mne[b*512+o]);
    float a  = g5[o] * RSQ;
    float bo = b5[o];
    float hv = lrelu((a >= 0.f ? a*mx : a*mn) + bo);
    h[o] = hv;
    out[b*512+o] = hv;
  }
  __syncthreads();
  const float* wr = Wemb + (size_t)t*512;
  float s = 0.f;
  for(int o=0;o<512;o+=4){
    float4 w4 = *(const float4*)(wr+o);
    s = fmaf(h[o],w4.x, fmaf(h[o+1],w4.y, fmaf(h[o+2],w4.z, fmaf(h[o+3],w4.w, s))));
  }
  out[4096 + b*256 + t] = s;
}

// ---------------- launch ----------------
extern "C" void kernel_launch(void* const* d_in, const int* in_sizes, int n_in,
                              void* d_out, int out_size, void* d_ws, size_t ws_size,
                              hipStream_t stream) {
  if (ws_size < WS_END * sizeof(float)) return;
  const bool big = ws_size >= WS_BIG_END * sizeof(float);   // deterministic per call

  const float* x0   = (const float*)d_in[0];
  const float* W1   = (const float*)d_in[1];
  const float* g1   = (const float*)d_in[2];
  const float* b1   = (const float*)d_in[3];
  const float* W2   = (const float*)d_in[4];
  const float* g2   = (const float*)d_in[5];
  const float* b2   = (const float*)d_in[6];
  const float* W3   = (const float*)d_in[7];
  const float* g3   = (const float*)d_in[8];
  const float* b3   = (const float*)d_in[9];
  const float* W4   = (const float*)d_in[10];
  const float* g4   = (const float*)d_in[11];
  const float* b4   = (const float*)d_in[12];
  const float* W5   = (const float*)d_in[13];
  const float* g5   = (const float*)d_in[14];
  const float* b5   = (const float*)d_in[15];
  const float* Wemb = (const float*)d_in[16];

  float* ws = (float*)d_ws;
  float* xx = ws + OFF_XX;
  float* x1 = ws + OFF_X1;  float* x2 = ws + OFF_X2;
  float* x3 = ws + OFF_X3;  float* x4 = ws + OFF_X4;
  float* qpS = ws + OFF_SC;               // L1 qp (width 128) + fallback chunked q/bs
  float* bsS = ws + OFF_SC + (size_t)BN*64;
  int*   id = (int*)(ws + OFF_ID);
  float* W5Tf = ws + OFF_W5T;
  unsigned* mxe = (unsigned*)(ws + OFF_MX);
  unsigned* mne = (unsigned*)(ws + OFF_MN);
  float* WT2 = ws + OFF_WT2;
  float* WT3 = ws + OFF_WT3;
  float* WT4 = ws + OFF_WT4;
  float* distD = ws + OFF_X3;   // fallback dual-batch
  float* distS = ws + OFF_X4;   // fallback single-batch
  float* distB = ws + OFF_BIG;  // big: 8-batch dist, then reused as qp buffer
  float* out = (float*)d_out;

  prep_k<<<1024,256,0,stream>>>(W5, W2, W3, W4, W5Tf, WT2, WT3, WT4, mxe, mne);

  // layer 1 (3 -> 64)
  sel3_k<<<BN*64/256,256,0,stream>>>(x0, id);
  qp3_k<<<BN*8/256,256,0,stream>>>(x0, W1, qpS);
  gather_qp_k<64><<<BN*64/256,256,0,stream>>>(qpS, id, g1, b1, x1);

  if(big){
    float* qpB = distB;                      // reuse dist region post-sel
    // layer 2 (CIN=64 -> COUT=64, qp width 128)
    sqnorm_k<64><<<BN/256,256,0,stream>>>(x1, xx);
    gemm_dist_k<64><<<dim3(16,16,8),256,0,stream>>>(x1, xx, distB, 0);
    sel_k<<<(8*NN)/4,256,0,stream>>>(distB, id, 0, 8*NN);
    qp_gemm_k<64,128><<<dim3(1,BN/128),256,0,stream>>>(x1, WT2, qpB);
    gather_qp_k<64><<<BN*64/256,256,0,stream>>>(qpB, id, g2, b2, x2);
    // layer 3 (64 -> 128, qp width 256)
    sqnorm_k<64><<<BN/256,256,0,stream>>>(x2, xx);
    gemm_dist_k<64><<<dim3(16,16,8),256,0,stream>>>(x2, xx, distB, 0);
    sel_k<<<(8*NN)/4,256,0,stream>>>(distB, id, 0, 8*NN);
    qp_gemm_k<64,256><<<dim3(2,BN/128),256,0,stream>>>(x2, WT3, qpB);
    gather_qp_k<128><<<BN*128/256,256,0,stream>>>(qpB, id, g3, b3, x3);
    // layer 4 (128 -> 256, qp width 512)
    sqnorm_k<128><<<BN/256,256,0,stream>>>(x3, xx);
    gemm_dist_k<128><<<dim3(16,16,8),256,0,stream>>>(x3, xx, distB, 0);
    sel_k<<<(8*NN)/4,256,0,stream>>>(distB, id, 0, 8*NN);
    qp_gemm_k<128,512><<<dim3(4,BN/128),256,0,stream>>>(x3, WT4, qpB);
    gather_qp_k<256><<<BN*256/256,256,0,stream>>>(qpB, id, g4, b4, x4);
  } else {
    // fallback: chunked (R12 structure, cat weight layout)
    sqnorm_k<64><<<BN/256,256,0,stream>>>(x1, xx);
    for(int r=0;r<4;r++){
      gemm_dist_k<64><<<dim3(16,16,2),256,0,stream>>>(x1, xx, distD, 2*r);
      sel_k<<<(2*NN)/4,256,0,stream>>>(distD, id, 2*r, 2*NN);
    }
    qp64T_k<64,64><<<BN*8/256,256,0,stream>>>(x1, WT2, 0, qpS, bsS);
    gather_chunk_k<64><<<BN*64/256,256,0,stream>>>(qpS, bsS, id, g2, b2, 0, x2);

    sqnorm_k<64><<<BN/256,256,0,stream>>>(x2, xx);
    for(int r=0;r<4;r++){
      gemm_dist_k<64><<<dim3(16,16,2),256,0,stream>>>(x2, xx, distD, 2*r);
      sel_k<<<(2*NN)/4,256,0,stream>>>(distD, id, 2*r, 2*NN);
    }
    for(int cb=0; cb<128; cb+=64){
      qp64T_k<64,128><<<BN*8/256,256,0,stream>>>(x2, WT3, cb, qpS, bsS);
      gather_chunk_k<128><<<BN*64/256,256,0,stream>>>(qpS, bsS, id, g3, b3, cb, x3);
    }

    sqnorm_k<128><<<BN/256,256,0,stream>>>(x3, xx);
    for(int r=0;r<8;r++){
      gemm_dist_k<128><<<dim3(16,16,1),256,0,stream>>>(x3, xx, distS, r);
      sel_k<<<NN/4,256,0,stream>>>(distS, id, r, NN);
    }
    for(int cb=0; cb<256; cb+=64){
      qp64T_k<128,256><<<BN*8/256,256,0,stream>>>(x3, WT4, cb, qpS, bsS);
      gather_chunk_k<256><<<BN*64/256,256,0,stream>>>(qpS, bsS, id, g4, b4, cb, x4);
    }
  }

  // head
  w5gemm_k<<<dim3(4,16,8),256,0,stream>>>(x1, x2, x3, x4, W5Tf, mxe, mne);
  final_k<<<BB,256,0,stream>>>(mxe, mne, g5, b5, Wemb, out);
}